// Round 1
// 1149.162 us; speedup vs baseline: 1.0626x; 1.0626x over previous
//
#include <hip/hip_runtime.h>
#include <math.h>

#define MDIM 20
#define ODIM 512
#define LSTR 21            // padded LDS row stride
#define NPAIR 210          // 20*21/2 unique Gram pairs
#define ROWS_PER_BLOCK 64

typedef float f4 __attribute__((ext_vector_type(4)));

// ---------------------------------------------------------------------------
// Kernel 1 (setup): compute Qt[20][512] = R^{-T} * W^T where W = weight+1e-8
// and R is the LAPACK-convention QR R-factor of W.
//
// Key identity: the Householder R of the 512x20 W (including diagonal signs)
// equals the Householder R of the 40x20 matrix [W_top; L^T], where
// L L^T = Gram(W rows 20..511). Reflector bottoms only enter via inner
// products (the Gram), which right-multiplicative updates preserve.
// All small math in fp64 -> our R is closer to exact than the fp32 reference.
// ---------------------------------------------------------------------------
__global__ __launch_bounds__(256) void setup_kernel(const float* __restrict__ w,
                                                    float* __restrict__ qt) {
  __shared__ float  Ws[ODIM * LSTR];     // 43 KB: W + 1e-8
  __shared__ double Gd[MDIM * 21];       // Gram -> Cholesky L (lower)
  __shared__ double Ad[40 * 21];         // [W_top; L^T] -> Householder workspace
  __shared__ double Rid[MDIM * 21];      // R^{-1} (upper)
  __shared__ double wcd[MDIM];
  __shared__ double sc[4];               // tau, vinv, beta
  const int tid = threadIdx.x;
  const int lane = tid & 63;
  const int wave = tid >> 6;

  // stage W + 1e-8 (coalesced)
  for (int i = tid; i < ODIM * MDIM; i += 256) {
    int r = i / MDIM, c = i - r * MDIM;
    Ws[r * LSTR + c] = w[i] + 1e-8f;
  }
  __syncthreads();

  // Gram of bottom rows 20..511, fp64, one pair per thread
  if (tid < NPAIR) {
    int rem = tid, i = 0;
    while (rem >= MDIM - i) { rem -= MDIM - i; ++i; }
    const int pi = i, pj = i + rem;
    double acc = 0.0;
    for (int r = MDIM; r < ODIM; ++r)
      acc += (double)Ws[r * LSTR + pi] * (double)Ws[r * LSTR + pj];
    Gd[pi * 21 + pj] = acc;
    Gd[pj * 21 + pi] = acc;
  }
  __syncthreads();

  // Cholesky (right-looking): lower triangle of Gd becomes L
  for (int k = 0; k < MDIM; ++k) {
    if (tid == 0) Gd[k * 21 + k] = sqrt(Gd[k * 21 + k]);
    __syncthreads();
    if (tid > k && tid < MDIM) Gd[tid * 21 + k] /= Gd[k * 21 + k];
    __syncthreads();
    if (tid > k && tid < MDIM) {
      double ljk = Gd[tid * 21 + k];
      for (int i = k + 1; i <= tid; ++i) Gd[tid * 21 + i] -= ljk * Gd[i * 21 + k];
    }
    __syncthreads();
  }

  // Ahat = [W_top; L^T]  (40 x 20)
  for (int idx = tid; idx < 40 * MDIM; idx += 256) {
    int r = idx / MDIM, c = idx - r * MDIM;
    double v;
    if (r < MDIM) v = (double)Ws[r * LSTR + c];
    else { int k = r - MDIM; v = (c >= k) ? Gd[c * 21 + k] : 0.0; }
    Ad[r * 21 + c] = v;
  }
  __syncthreads();

  // Householder QR of 40x20, exact LAPACK sgeqf2/slarfg convention
  for (int j = 0; j < MDIM; ++j) {
    if (tid < 64) {  // xnorm^2 over rows j+1..39 of column j (wave 0)
      double x = (tid > j && tid < 40) ? Ad[tid * 21 + j] : 0.0;
      double s = x * x;
      #pragma unroll
      for (int off = 32; off > 0; off >>= 1) s += __shfl_down(s, off, 64);
      if (tid == 0) {
        double alpha = Ad[j * 21 + j];
        double beta, tau, vinv;
        if (s == 0.0) { beta = alpha; tau = 0.0; vinv = 0.0; }
        else {
          beta = -copysign(sqrt(alpha * alpha + s), alpha);
          tau = (beta - alpha) / beta;
          vinv = 1.0 / (alpha - beta);
        }
        sc[0] = tau; sc[1] = vinv; sc[2] = beta;
      }
    }
    __syncthreads();
    const double tau = sc[0], vinv = sc[1];
    if (tid > j && tid < 40) Ad[tid * 21 + j] *= vinv;   // scale v (v_j = 1)
    __syncthreads();
    // wc[c] = tau * (A[j][c] + sum_{r>j} v_r A[r][c]),  c = j+1..19
    for (int c = j + 1 + wave; c < MDIM; c += 4) {
      double val = 0.0;
      if (lane == j) val = Ad[j * 21 + c];
      else if (lane > j && lane < 40) val = Ad[lane * 21 + j] * Ad[lane * 21 + c];
      #pragma unroll
      for (int off = 32; off > 0; off >>= 1) val += __shfl_down(val, off, 64);
      if (lane == 0) wcd[c] = tau * val;
    }
    __syncthreads();
    // trailing update A[r][c] -= v_r * wc[c], r = j..39, c = j+1..19
    const int ncols = MDIM - 1 - j;
    if (ncols > 0) {
      const int total = (40 - j) * ncols;
      for (int idx = tid; idx < total; idx += 256) {
        int r = j + idx / ncols, c = j + 1 + idx % ncols;
        double v = (r == j) ? 1.0 : Ad[r * 21 + j];
        Ad[r * 21 + c] -= v * wcd[c];
      }
    }
    if (tid == 0) Ad[j * 21 + j] = sc[2];  // diag = beta (col j untouched above)
    __syncthreads();
  }

  // Rinv = R^{-1} (upper): one column per thread, back substitution
  if (tid < MDIM) {
    const int c = tid;
    Rid[c * 21 + c] = 1.0 / Ad[c * 21 + c];
    for (int i = c - 1; i >= 0; --i) {
      double s = 0.0;
      for (int k = i + 1; k <= c; ++k) s += Ad[i * 21 + k] * Rid[k * 21 + c];
      Rid[i * 21 + c] = -s / Ad[i * 21 + i];
    }
  }
  __syncthreads();

  // Qt[m][o] = Q[o][m] = sum_{k<=m} W[o][k] * Rinv[k][m]
  for (int o = tid; o < ODIM; o += 256) {
    #pragma unroll
    for (int m = 0; m < MDIM; ++m) {
      double acc = 0.0;
      #pragma unroll
      for (int k = 0; k <= m; ++k)
        acc += (double)Ws[o * LSTR + k] * Rid[k * 21 + m];
      qt[m * ODIM + o] = (float)acc;
    }
  }
}

// ---------------------------------------------------------------------------
// Kernel 2 (unchanged): out[b][o] = sum_m input[b][m] * Qt[m][o]
// 256 threads, 64 rows/block; Q fragment in registers; input tile in LDS.
// ---------------------------------------------------------------------------
__global__ __launch_bounds__(256, 4) void matmul_kernel(
    const float* __restrict__ in, const float* __restrict__ qt,
    float* __restrict__ out, int batch) {
  __shared__ f4 tile4[ROWS_PER_BLOCK * MDIM / 4];  // 64 rows * 20 fl = 5 KiB
  const int tid = threadIdx.x;
  const int oq = tid & 127;   // float4 index within the 512-wide output row
  const int grp = tid >> 7;   // 0 or 1: which half of the row tile
  const int base = blockIdx.x * ROWS_PER_BLOCK;
  int nrows = batch - base;
  if (nrows > ROWS_PER_BLOCK) nrows = ROWS_PER_BLOCK;

  const f4* in4 = (const f4*)(in + (size_t)base * MDIM);
  const int nf4 = nrows * MDIM / 4;
  for (int i = tid; i < nf4; i += 256) tile4[i] = in4[i];

  const f4* qt4 = (const f4*)qt;
  f4 qv[MDIM];
  #pragma unroll
  for (int m = 0; m < MDIM; ++m) qv[m] = qt4[m * 128 + oq];
  __syncthreads();

  f4* out4 = (f4*)out;
  const float* tile = (const float*)tile4;
  #pragma unroll 1
  for (int it = 0; it < ROWS_PER_BLOCK / 2; ++it) {
    const int lr = grp * (ROWS_PER_BLOCK / 2) + it;
    if (lr >= nrows) break;
    const f4* row4 = (const f4*)(tile + lr * MDIM);
    f4 xv[5];
    #pragma unroll
    for (int k = 0; k < 5; ++k) xv[k] = row4[k];
    f4 acc = (f4)(0.f);
    #pragma unroll
    for (int m = 0; m < MDIM; ++m) {
      float x = xv[m / 4][m % 4];
      acc += x * qv[m];
    }
    __builtin_nontemporal_store(acc, &out4[(size_t)(base + lr) * 128 + oq]);
  }
}

extern "C" void kernel_launch(void* const* d_in, const int* in_sizes, int n_in,
                              void* d_out, int out_size, void* d_ws, size_t ws_size,
                              hipStream_t stream) {
  const float* input = (const float*)d_in[0];   // [batch, 20] fp32
  const float* weight = (const float*)d_in[1];  // [512, 20] fp32
  float* out = (float*)d_out;                   // [batch, 512] fp32
  float* qt = (float*)d_ws;                     // Qt[20][512] scratch (40 KiB)
  const int batch = in_sizes[0] / MDIM;

  setup_kernel<<<1, 256, 0, stream>>>(weight, qt);
  const int blocks = (batch + ROWS_PER_BLOCK - 1) / ROWS_PER_BLOCK;
  matmul_kernel<<<blocks, 256, 0, stream>>>(input, qt, out, batch);
}